// Round 15
// baseline (838.785 us; speedup 1.0000x reference)
//
#include <hip/hip_runtime.h>
#include <math.h>

#define BB 2
#define LL 2048
#define MM 1024
#define DD 16
#define RR 64
#define NN 96
#define BLROWS (BB*LL)          // 4096
#define NCH 64                  // chunks
#define CLEN (LL/NCH)           // 32

#define LOG2E 1.44269504088896340736f

// workspace layout (float offsets). dt region holds bf16 (ushort).
#define OFF_XP    0
#define OFF_DT    (OFF_XP + BLROWS*NN)            // 393216
#define OFF_A2    (OFF_DT + BLROWS*MM/2)          // 2490368
#define OFF_HEND  (OFF_A2 + MM*DD)                // 2506752
#define OFF_DTSUM (OFF_HEND + NCH*BB*MM*DD)       // 4603904
#define OFF_BAR   (OFF_DTSUM + NCH*BB*MM)         // 4735232 (1 uint)
// total = 4735233 floats = 18.9 MB

typedef __attribute__((ext_vector_type(8))) short bf16x8;
typedef __attribute__((ext_vector_type(4))) float f32x4;
typedef __attribute__((ext_vector_type(4))) unsigned short u16x4;

union BF8 { bf16x8 v; unsigned u[4]; uint4 q; };

// packed f32x2 -> bf16x2 (RNE): dst = {hi=bf16(b), lo=bf16(a)}
__device__ __forceinline__ unsigned cvtpk(float a, float b) {
  unsigned r;
  asm("v_cvt_pk_bf16_f32 %0, %1, %2" : "=v"(r) : "v"(a), "v"(b));
  return r;
}

// bare v_exp_f32: computes 2^x (operand must be pre-scaled by log2e)
__device__ __forceinline__ float vexp2(float x) {
  float r;
  asm("v_exp_f32 %0, %1" : "=v"(r) : "v"(x));
  return r;
}

// fast softplus: log(1+e^v) via native v_exp/v_log
__device__ __forceinline__ float softplusf(float v) {
  return v > 20.f ? v : __logf(1.f + __expf(v));
}

// f32 -> bf16 round-to-nearest-even (scalar)
__device__ __forceinline__ short f2bf(float f) {
  union { float f; unsigned u; } v; v.f = f;
  unsigned r = v.u + 0x7FFFu + ((v.u >> 16) & 1u);
  return (short)(r >> 16);
}

// cross-lane xor-1 / xor-2 via DPP quad_perm (VALU pipe)
__device__ __forceinline__ float dpp_xor1(float v) {
  int i = __builtin_amdgcn_mov_dpp(__float_as_int(v), 0xB1, 0xF, 0xF, true);
  return __int_as_float(i);
}
__device__ __forceinline__ float dpp_xor2(float v) {
  int i = __builtin_amdgcn_mov_dpp(__float_as_int(v), 0x4E, 0xF, 0xF, true);
  return __int_as_float(i);
}

// ---------------- xp = x @ W^T (4096 x 96, K=1024) via bf16 MFMA ----------------
// blocks [0,768): GEMM, one wave per 16-row x 32-col tile (2 n-tiles, A loaded once).
// blocks [768,1024): A2 = -exp(A_log)^T * log2e prep; also zeroes the grid barrier.
#define XP_GEMM_BLOCKS ((BLROWS/16)*3)   // 768
__global__ __launch_bounds__(64) void k_xp(const float* __restrict__ x,
                                           const float* __restrict__ W,
                                           const float* __restrict__ A_log,
                                           float* __restrict__ ws) {
  if (blockIdx.x >= XP_GEMM_BLOCKS) {
    int idx = (blockIdx.x - XP_GEMM_BLOCKS) * 64 + threadIdx.x;
    int m = idx >> 4, d = idx & 15;
    ws[OFF_A2 + idx] = -__expf(A_log[d * MM + m]) * LOG2E;
    if (idx == 0) ((unsigned*)(ws + OFF_BAR))[0] = 0u;   // reset grid barrier
    return;
  }
  float* xp = ws + OFF_XP;
  int lane = threadIdx.x;
  int rt = blockIdx.x / 3, np = blockIdx.x % 3;
  int lr = lane & 15, lk = lane >> 4;
  const float* xr = x + (size_t)(rt * 16 + lr) * MM + lk * 8;
  const float* wr0 = W + (size_t)(np * 32 + lr) * MM + lk * 8;
  const float* wr1 = W + (size_t)(np * 32 + 16 + lr) * MM + lk * 8;
  f32x4 acc0 = {0.f, 0.f, 0.f, 0.f}, acc1 = {0.f, 0.f, 0.f, 0.f};
#pragma unroll 2
  for (int kk = 0; kk < MM; kk += 32) {
    float4 xa = *(const float4*)(xr + kk);
    float4 xb = *(const float4*)(xr + kk + 4);
    float4 p0 = *(const float4*)(wr0 + kk);
    float4 p1 = *(const float4*)(wr0 + kk + 4);
    float4 q0 = *(const float4*)(wr1 + kk);
    float4 q1 = *(const float4*)(wr1 + kk + 4);
    BF8 a, b0, b1;
    a.u[0] = cvtpk(xa.x, xa.y); a.u[1] = cvtpk(xa.z, xa.w);
    a.u[2] = cvtpk(xb.x, xb.y); a.u[3] = cvtpk(xb.z, xb.w);
    b0.u[0] = cvtpk(p0.x, p0.y); b0.u[1] = cvtpk(p0.z, p0.w);
    b0.u[2] = cvtpk(p1.x, p1.y); b0.u[3] = cvtpk(p1.z, p1.w);
    b1.u[0] = cvtpk(q0.x, q0.y); b1.u[1] = cvtpk(q0.z, q0.w);
    b1.u[2] = cvtpk(q1.x, q1.y); b1.u[3] = cvtpk(q1.z, q1.w);
    acc0 = __builtin_amdgcn_mfma_f32_16x16x32_bf16(a.v, b0.v, acc0, 0, 0, 0);
    acc1 = __builtin_amdgcn_mfma_f32_16x16x32_bf16(a.v, b1.v, acc1, 0, 0, 0);
  }
  int r0 = rt * 16 + lk * 4, c0 = np * 32 + lr;
#pragma unroll
  for (int e = 0; e < 4; ++e) {
    xp[(size_t)(r0 + e) * NN + c0] = acc0[e];
    xp[(size_t)(r0 + e) * NN + c0 + 16] = acc1[e];
  }
}

// ---------------- dt = softplus(xp[:, :64] @ dtW^T + b), bf16 out, via MFMA ----------------
__global__ __launch_bounds__(64) void k_dt(const float* __restrict__ dtW,
                                           const float* __restrict__ dtb,
                                           float* __restrict__ ws) {
  const float* xp = ws + OFF_XP;
  unsigned short* dt16 = (unsigned short*)(ws + OFF_DT);
  int lane = threadIdx.x;
  int rt = blockIdx.x >> 3, mg = blockIdx.x & 7;
  int lr = lane & 15, lk = lane >> 4;
  const float* xr = xp + (size_t)(rt * 16 + lr) * NN + lk * 8;
  BF8 a0, a1;
  {
    float4 xa = *(const float4*)(xr);
    float4 xb = *(const float4*)(xr + 4);
    float4 xc = *(const float4*)(xr + 32);
    float4 xd = *(const float4*)(xr + 36);
    a0.u[0] = cvtpk(xa.x, xa.y); a0.u[1] = cvtpk(xa.z, xa.w);
    a0.u[2] = cvtpk(xb.x, xb.y); a0.u[3] = cvtpk(xb.z, xb.w);
    a1.u[0] = cvtpk(xc.x, xc.y); a1.u[1] = cvtpk(xc.z, xc.w);
    a1.u[2] = cvtpk(xd.x, xd.y); a1.u[3] = cvtpk(xd.z, xd.w);
  }
  int r0 = rt * 16 + lk * 4;
#pragma unroll 2
  for (int mt = 0; mt < 8; ++mt) {
    int mcol = (mg * 8 + mt) * 16 + lr;
    const float* wr = dtW + (size_t)mcol * RR + lk * 8;
    float4 p0 = *(const float4*)(wr);
    float4 p1 = *(const float4*)(wr + 4);
    float4 p2 = *(const float4*)(wr + 32);
    float4 p3 = *(const float4*)(wr + 36);
    BF8 b0, b1;
    b0.u[0] = cvtpk(p0.x, p0.y); b0.u[1] = cvtpk(p0.z, p0.w);
    b0.u[2] = cvtpk(p1.x, p1.y); b0.u[3] = cvtpk(p1.z, p1.w);
    b1.u[0] = cvtpk(p2.x, p2.y); b1.u[1] = cvtpk(p2.z, p2.w);
    b1.u[2] = cvtpk(p3.x, p3.y); b1.u[3] = cvtpk(p3.z, p3.w);
    f32x4 acc = {0.f, 0.f, 0.f, 0.f};
    acc = __builtin_amdgcn_mfma_f32_16x16x32_bf16(a0.v, b0.v, acc, 0, 0, 0);
    acc = __builtin_amdgcn_mfma_f32_16x16x32_bf16(a1.v, b1.v, acc, 0, 0, 0);
    float bv = dtb[mcol];
#pragma unroll
    for (int e = 0; e < 4; ++e)
      dt16[(size_t)(r0 + e) * MM + mcol] = (unsigned short)f2bf(softplusf(acc[e] + bv));
  }
}

// ---------------- fused scan: phase1 (chunk h_end) -> barrier -> chunk scan -> barrier -> phase3 (y) ----------------
// grid 1024 x 512 = exactly 4 blocks/CU x 256 CU co-resident (36KB LDS, <=64 VGPR, 2048 thr/CU).
// Block = (mw 0..7, c 0..63, b 0..1) covering 128 m's. Thread = (ml = t>>2, dsub = t&3).
// Chunk tiles (dt+x packed bf16, z f32, B/C f32) staged in LDS ONCE, retained across barriers.
__global__ __launch_bounds__(512, 8) void k_scan(const float* __restrict__ x,
                                                 const float* __restrict__ z,
                                                 const float* __restrict__ Dp,
                                                 float* __restrict__ out,
                                                 float* __restrict__ ws) {
  const float* xp = ws + OFF_XP;
  const float* A2t = ws + OFF_A2;
  float* hend = ws + OFF_HEND;
  float* dtsum = ws + OFF_DTSUM;
  unsigned* bar = (unsigned*)(ws + OFF_BAR);
  __shared__ __align__(16) unsigned dtxs[CLEN * 128];   // 16KB: hi=bf16(x), lo=bf16(dt)
  __shared__ __align__(16) float zs[CLEN * 128];        // 16KB
  __shared__ __align__(16) float bs[CLEN * 32];         // 4KB: B cols 0-15, C cols 16-31
  int bid = blockIdx.x;
  int mw = bid & 7, c = (bid >> 3) & (NCH - 1), b = bid >> 9;
  int t = threadIdx.x;
  int ml = t >> 2, dsub = t & 3;
  int m0 = mw * 128, m = m0 + ml;
  int l0 = c * CLEN;
  const unsigned short* dtg = (const unsigned short*)(ws + OFF_DT) + (size_t)(b * LL + l0) * MM + m0;
  const float* xg = x + (size_t)(b * LL + l0) * MM + m0;
  const float* zg = z + (size_t)(b * LL + l0) * MM + m0;
#pragma unroll
  for (int i = t; i < CLEN * 32; i += 512) {
    int lo = i >> 5, q = i & 31;
    u16x4 dv = *(const u16x4*)&dtg[(size_t)lo * MM + q * 4];
    float4 xv = *(const float4*)&xg[(size_t)lo * MM + q * 4];
    unsigned xp01 = cvtpk(xv.x, xv.y), xp23 = cvtpk(xv.z, xv.w);
    uint4 o;
    o.x = ((xp01 & 0xffffu) << 16) | (unsigned)dv[0];
    o.y = (xp01 & 0xffff0000u) | (unsigned)dv[1];
    o.z = ((xp23 & 0xffffu) << 16) | (unsigned)dv[2];
    o.w = (xp23 & 0xffff0000u) | (unsigned)dv[3];
    *(uint4*)&dtxs[lo * 128 + q * 4] = o;
    *(float4*)&zs[lo * 128 + q * 4] = *(const float4*)&zg[(size_t)lo * MM + q * 4];
  }
#pragma unroll
  for (int i = t; i < CLEN * 32; i += 512) {
    int r = i >> 5, cc = i & 31;
    bs[i] = xp[(size_t)(b * LL + l0 + r) * NN + RR + cc];
  }
  __syncthreads();
  float4 A2v = *(const float4*)&A2t[m * DD + dsub * 4];
  // ---- phase 1: chunk-local h_end (h0=0) and sum(dt) ----
  float h0_ = 0.f, h1_ = 0.f, h2_ = 0.f, h3_ = 0.f, S = 0.f;
#pragma unroll 4
  for (int lo = 0; lo < CLEN; ++lo) {
    unsigned p = dtxs[lo * 128 + ml];
    float dtv = __uint_as_float(p << 16);
    float xv = __uint_as_float(p & 0xffff0000u);
    float4 Bv = *(const float4*)&bs[lo * 32 + dsub * 4];
    S += dtv;
    float dtx = dtv * xv;
    h0_ = vexp2(dtv * A2v.x) * h0_ + dtx * Bv.x;
    h1_ = vexp2(dtv * A2v.y) * h1_ + dtx * Bv.y;
    h2_ = vexp2(dtv * A2v.z) * h2_ + dtx * Bv.z;
    h3_ = vexp2(dtv * A2v.w) * h3_ + dtx * Bv.w;
  }
  size_t o = ((size_t)((c * BB + b) * MM + m)) * DD + dsub * 4;
  *(float4*)&hend[o] = make_float4(h0_, h1_, h2_, h3_);
  if (dsub == 0) dtsum[(c * BB + b) * MM + m] = S;
  // ---- grid barrier 1 ----
  __threadfence();
  __syncthreads();
  if (t == 0) {
    __hip_atomic_fetch_add(bar, 1u, __ATOMIC_ACQ_REL, __HIP_MEMORY_SCOPE_AGENT);
    while (__hip_atomic_load(bar, __ATOMIC_ACQUIRE, __HIP_MEMORY_SCOPE_AGENT) < 1024u)
      __builtin_amdgcn_s_sleep(1);
  }
  __syncthreads();
  __threadfence();
  // ---- phase 2: inter-chunk scan (blocks 0..63 = 32768 threads), h0 overwrites hend ----
  if (bid < 64) {
    int tt = bid * 512 + t;
    int d = tt & 15, m2 = (tt >> 4) & 1023, b2 = tt >> 14;
    float A2 = A2t[m2 * DD + d];
    const size_t hstride = (size_t)BB * MM * DD;
    const int sstride = BB * MM;
    size_t oo = ((size_t)b2 * MM + m2) * DD + d;
    int si = b2 * MM + m2;
    float h = 0.f;
    float he = hend[oo], Sv = dtsum[si];
    for (int c2 = 0; c2 < NCH; ++c2) {
      float heN = 0.f, SN = 0.f;
      if (c2 + 1 < NCH) {
        heN = hend[oo + hstride];
        SN = dtsum[si + sstride];
      }
      hend[oo] = h;
      h = vexp2(A2 * Sv) * h + he;
      he = heN; Sv = SN;
      oo += hstride; si += sstride;
    }
  }
  // ---- grid barrier 2 ----
  __threadfence();
  __syncthreads();
  if (t == 0) {
    __hip_atomic_fetch_add(bar, 1u, __ATOMIC_ACQ_REL, __HIP_MEMORY_SCOPE_AGENT);
    while (__hip_atomic_load(bar, __ATOMIC_ACQUIRE, __HIP_MEMORY_SCOPE_AGENT) < 2048u)
      __builtin_amdgcn_s_sleep(1);
  }
  __syncthreads();
  __threadfence();
  // ---- phase 3: recompute with true h0 (LDS retained), emit y * silu(z) ----
  float4 hv = *(const float4*)&hend[o];
  h0_ = hv.x; h1_ = hv.y; h2_ = hv.z; h3_ = hv.w;
  float Dpm = Dp[m];
  size_t idx = ((size_t)(b * LL + l0)) * MM + m;
#pragma unroll 4
  for (int lo = 0; lo < CLEN; ++lo) {
    unsigned p = dtxs[lo * 128 + ml];
    float dtv = __uint_as_float(p << 16);
    float xv = __uint_as_float(p & 0xffff0000u);
    float zv = zs[lo * 128 + ml];
    float4 Bv = *(const float4*)&bs[lo * 32 + dsub * 4];
    float4 Cv = *(const float4*)&bs[lo * 32 + DD + dsub * 4];
    float dtx = dtv * xv;
    h0_ = vexp2(dtv * A2v.x) * h0_ + dtx * Bv.x;
    h1_ = vexp2(dtv * A2v.y) * h1_ + dtx * Bv.y;
    h2_ = vexp2(dtv * A2v.z) * h2_ + dtx * Bv.z;
    h3_ = vexp2(dtv * A2v.w) * h3_ + dtx * Bv.w;
    float yp = h0_ * Cv.x + h1_ * Cv.y + h2_ * Cv.z + h3_ * Cv.w;
    yp += dpp_xor1(yp);
    yp += dpp_xor2(yp);
    float sig = __builtin_amdgcn_rcpf(1.f + vexp2(-LOG2E * zv));
    if (dsub == 0)
      out[idx + (size_t)lo * MM] = (yp + Dpm * xv) * zv * sig;
  }
}

extern "C" void kernel_launch(void* const* d_in, const int* in_sizes, int n_in,
                              void* d_out, int out_size, void* d_ws, size_t ws_size,
                              hipStream_t stream) {
  const float* x = (const float*)d_in[0];
  const float* z = (const float*)d_in[1];
  const float* W = (const float*)d_in[2];
  const float* dtW = (const float*)d_in[3];
  const float* dtb = (const float*)d_in[4];
  const float* A_log = (const float*)d_in[5];
  const float* Dp = (const float*)d_in[6];
  float* out = (float*)d_out;
  float* ws = (float*)d_ws;

  k_xp<<<XP_GEMM_BLOCKS + (MM * DD / 64), 64, 0, stream>>>(x, W, A_log, ws);
  k_dt<<<(BLROWS / 16) * 8, 64, 0, stream>>>(dtW, dtb, ws);
  k_scan<<<8 * NCH * BB, 512, 0, stream>>>(x, z, Dp, out, ws);
}

// Round 16
// 81.189 us; speedup vs baseline: 10.3313x; 10.3313x over previous
//
#include <hip/hip_runtime.h>
#include <math.h>

#define BB 2
#define LL 2048
#define MM 1024
#define DD 16
#define RR 64
#define NN 96
#define BLROWS (BB*LL)          // 4096
#define NCH 64                  // chunks
#define CLEN (LL/NCH)           // 32

#define LOG2E 1.44269504088896340736f

// workspace layout (float offsets). dt/WB/DWB regions hold bf16 (ushort).
#define OFF_XP    0
#define OFF_DT    (OFF_XP + BLROWS*NN)            // 393216
#define OFF_A2    (OFF_DT + BLROWS*MM/2)          // 2490368
#define OFF_HEND  (OFF_A2 + MM*DD)                // 2506752
#define OFF_DTSUM (OFF_HEND + NCH*BB*MM*DD)       // 4603904
#define OFF_WB    (OFF_DTSUM + NCH*BB*MM)         // 4734976 (W bf16: 98304 u16)
#define OFF_DWB   (OFF_WB + MM*NN/2)              // 4784128 (dtW bf16: 65536 u16)
// total = OFF_DWB + RR*MM/2 = 4816896 floats = 19.3 MB

typedef __attribute__((ext_vector_type(8))) short bf16x8;
typedef __attribute__((ext_vector_type(4))) float f32x4;
typedef __attribute__((ext_vector_type(4))) unsigned short u16x4;

union BF8 { bf16x8 v; unsigned u[4]; uint4 q; };

// packed f32x2 -> bf16x2 (RNE): dst = {hi=bf16(b), lo=bf16(a)}
__device__ __forceinline__ unsigned cvtpk(float a, float b) {
  unsigned r;
  asm("v_cvt_pk_bf16_f32 %0, %1, %2" : "=v"(r) : "v"(a), "v"(b));
  return r;
}

// bare v_exp_f32: computes 2^x (operand must be pre-scaled by log2e)
__device__ __forceinline__ float vexp2(float x) {
  float r;
  asm("v_exp_f32 %0, %1" : "=v"(r) : "v"(x));
  return r;
}

// fast softplus: log(1+e^v) via native v_exp/v_log
__device__ __forceinline__ float softplusf(float v) {
  return v > 20.f ? v : __logf(1.f + __expf(v));
}

// f32 -> bf16 round-to-nearest-even (scalar)
__device__ __forceinline__ short f2bf(float f) {
  union { float f; unsigned u; } v; v.f = f;
  unsigned r = v.u + 0x7FFFu + ((v.u >> 16) & 1u);
  return (short)(r >> 16);
}

__device__ __forceinline__ float bf2f(unsigned short u) {
  return __uint_as_float((unsigned)u << 16);
}

// cross-lane xor-1 / xor-2 via DPP quad_perm (VALU pipe, not LDS pipe)
__device__ __forceinline__ float dpp_xor1(float v) {
  int i = __builtin_amdgcn_mov_dpp(__float_as_int(v), 0xB1, 0xF, 0xF, true);
  return __int_as_float(i);
}
__device__ __forceinline__ float dpp_xor2(float v) {
  int i = __builtin_amdgcn_mov_dpp(__float_as_int(v), 0x4E, 0xF, 0xF, true);
  return __int_as_float(i);
}

// ---------------- prep: W->bf16, dtW->bf16, A2 = -exp(A_log)^T * log2e ----------------
__global__ __launch_bounds__(256) void k_prep(const float* __restrict__ W,
                                              const float* __restrict__ dtW,
                                              const float* __restrict__ A_log,
                                              float* __restrict__ ws) {
  int idx = blockIdx.x * 256 + threadIdx.x;
  if (idx < 24576) {
    float4 v = *(const float4*)&W[idx * 4];
    uint2 p; p.x = cvtpk(v.x, v.y); p.y = cvtpk(v.z, v.w);
    *(uint2*)&((unsigned short*)(ws + OFF_WB))[idx * 4] = p;
  } else if (idx < 24576 + 16384) {
    int j = idx - 24576;
    float4 v = *(const float4*)&dtW[j * 4];
    uint2 p; p.x = cvtpk(v.x, v.y); p.y = cvtpk(v.z, v.w);
    *(uint2*)&((unsigned short*)(ws + OFF_DWB))[j * 4] = p;
  } else if (idx < 24576 + 16384 + 16384) {
    int j = idx - 24576 - 16384;
    int m = j >> 4, d = j & 15;
    ws[OFF_A2 + j] = -__expf(A_log[d * MM + m]) * LOG2E;
  }
}

// ---------------- xp = x @ W^T (4096 x 96, K=1024) via bf16 MFMA ----------------
__global__ __launch_bounds__(64) void k_xp(const float* __restrict__ x,
                                           float* __restrict__ ws) {
  float* xp = ws + OFF_XP;
  const unsigned short* wb16 = (const unsigned short*)(ws + OFF_WB);
  int lane = threadIdx.x;
  int rt = blockIdx.x / 3, np = blockIdx.x % 3;
  int lr = lane & 15, lk = lane >> 4;
  const float* xr = x + (size_t)(rt * 16 + lr) * MM + lk * 8;
  const unsigned short* wr0 = wb16 + (size_t)(np * 32 + lr) * MM + lk * 8;
  const unsigned short* wr1 = wb16 + (size_t)(np * 32 + 16 + lr) * MM + lk * 8;
  f32x4 acc0 = {0.f, 0.f, 0.f, 0.f}, acc1 = {0.f, 0.f, 0.f, 0.f};
#pragma unroll 4
  for (int kk = 0; kk < MM; kk += 32) {
    float4 xa = *(const float4*)(xr + kk);
    float4 xb = *(const float4*)(xr + kk + 4);
    BF8 a, b0, b1;
    b0.q = *(const uint4*)(wr0 + kk);
    b1.q = *(const uint4*)(wr1 + kk);
    a.u[0] = cvtpk(xa.x, xa.y); a.u[1] = cvtpk(xa.z, xa.w);
    a.u[2] = cvtpk(xb.x, xb.y); a.u[3] = cvtpk(xb.z, xb.w);
    acc0 = __builtin_amdgcn_mfma_f32_16x16x32_bf16(a.v, b0.v, acc0, 0, 0, 0);
    acc1 = __builtin_amdgcn_mfma_f32_16x16x32_bf16(a.v, b1.v, acc1, 0, 0, 0);
  }
  int r0 = rt * 16 + lk * 4, c0 = np * 32 + lr;
#pragma unroll
  for (int e = 0; e < 4; ++e) {
    xp[(size_t)(r0 + e) * NN + c0] = acc0[e];
    xp[(size_t)(r0 + e) * NN + c0 + 16] = acc1[e];
  }
}

// ---------------- dt = softplus(xp[:, :64] @ dtW^T + b), bf16 out, via MFMA ----------------
__global__ __launch_bounds__(64) void k_dt(const float* __restrict__ dtb,
                                           float* __restrict__ ws) {
  const float* xp = ws + OFF_XP;
  const unsigned short* dwb16 = (const unsigned short*)(ws + OFF_DWB);
  unsigned short* dt16 = (unsigned short*)(ws + OFF_DT);
  int lane = threadIdx.x;
  int rt = blockIdx.x >> 3, mg = blockIdx.x & 7;
  int lr = lane & 15, lk = lane >> 4;
  const float* xr = xp + (size_t)(rt * 16 + lr) * NN + lk * 8;
  BF8 a0, a1;
  {
    float4 xa = *(const float4*)(xr);
    float4 xb = *(const float4*)(xr + 4);
    float4 xc = *(const float4*)(xr + 32);
    float4 xd = *(const float4*)(xr + 36);
    a0.u[0] = cvtpk(xa.x, xa.y); a0.u[1] = cvtpk(xa.z, xa.w);
    a0.u[2] = cvtpk(xb.x, xb.y); a0.u[3] = cvtpk(xb.z, xb.w);
    a1.u[0] = cvtpk(xc.x, xc.y); a1.u[1] = cvtpk(xc.z, xc.w);
    a1.u[2] = cvtpk(xd.x, xd.y); a1.u[3] = cvtpk(xd.z, xd.w);
  }
  int r0 = rt * 16 + lk * 4;
#pragma unroll 2
  for (int mt = 0; mt < 8; ++mt) {
    int mcol = (mg * 8 + mt) * 16 + lr;
    const unsigned short* wr = dwb16 + (size_t)mcol * RR + lk * 8;
    BF8 b0, b1;
    b0.q = *(const uint4*)(wr);
    b1.q = *(const uint4*)(wr + 32);
    f32x4 acc = {0.f, 0.f, 0.f, 0.f};
    acc = __builtin_amdgcn_mfma_f32_16x16x32_bf16(a0.v, b0.v, acc, 0, 0, 0);
    acc = __builtin_amdgcn_mfma_f32_16x16x32_bf16(a1.v, b1.v, acc, 0, 0, 0);
    float bv = dtb[mcol];
#pragma unroll
    for (int e = 0; e < 4; ++e)
      dt16[(size_t)(r0 + e) * MM + mcol] = (unsigned short)f2bf(softplusf(acc[e] + bv));
  }
}

// ---------------- scan phase 1: per-chunk h_end and sum(dt) ----------------
// d-split x4: thread = (m, d-quartet). grid 16*NCH*BB = 2048 wgs, block 256.
__global__ __launch_bounds__(256) void k_scan1(const float* __restrict__ x,
                                               float* __restrict__ ws) {
  const float* xp = ws + OFF_XP;
  const float* A2t = ws + OFF_A2;
  float* hend = ws + OFF_HEND;
  float* dtsum = ws + OFF_DTSUM;
  __shared__ __align__(16) float ds_[CLEN * 64];
  __shared__ __align__(16) float xs_[CLEN * 64];
  __shared__ __align__(16) float bs[CLEN * DD];
  int wg = blockIdx.x;
  int mw = wg & 15, c = (wg >> 4) & (NCH - 1), b = wg >> 10;
  int t = threadIdx.x;
  int ml = t >> 2, dsub = t & 3;
  int m0 = mw * 64, m = m0 + ml;
  int l0 = c * CLEN;
  const unsigned short* dtg = (const unsigned short*)(ws + OFF_DT) + (size_t)(b * LL + l0) * MM + m0;
  const float* xg = x + (size_t)(b * LL + l0) * MM + m0;
#pragma unroll
  for (int i = t; i < CLEN * 16; i += 256) {
    int lo = i >> 4, q = i & 15;
    u16x4 dv = *(const u16x4*)&dtg[(size_t)lo * MM + q * 4];
    *(float4*)&ds_[lo * 64 + q * 4] = make_float4(bf2f(dv[0]), bf2f(dv[1]), bf2f(dv[2]), bf2f(dv[3]));
    *(float4*)&xs_[lo * 64 + q * 4] = *(const float4*)&xg[(size_t)lo * MM + q * 4];
  }
  for (int i = t; i < CLEN * DD; i += 256) {
    int r = i >> 4, cc = i & 15;
    bs[i] = xp[(size_t)(b * LL + l0 + r) * NN + RR + cc];
  }
  __syncthreads();
  float4 A2v = *(const float4*)&A2t[m * DD + dsub * 4];
  float h0_ = 0.f, h1_ = 0.f, h2_ = 0.f, h3_ = 0.f, S = 0.f;
#pragma unroll 4
  for (int lo = 0; lo < CLEN; ++lo) {
    float dtv = ds_[lo * 64 + ml];
    float xv = xs_[lo * 64 + ml];
    float4 Bv = *(const float4*)&bs[lo * DD + dsub * 4];
    S += dtv;
    float dtx = dtv * xv;
    h0_ = vexp2(dtv * A2v.x) * h0_ + dtx * Bv.x;
    h1_ = vexp2(dtv * A2v.y) * h1_ + dtx * Bv.y;
    h2_ = vexp2(dtv * A2v.z) * h2_ + dtx * Bv.z;
    h3_ = vexp2(dtv * A2v.w) * h3_ + dtx * Bv.w;
  }
  size_t o = ((size_t)((c * BB + b) * MM + m)) * DD + dsub * 4;
  *(float4*)&hend[o] = make_float4(h0_, h1_, h2_, h3_);
  if (dsub == 0) dtsum[(c * BB + b) * MM + m] = S;
}

// ---------------- scan phase 2: scan over chunks (software-pipelined), h0 in place ----------------
__global__ __launch_bounds__(256) void k_scan2(float* __restrict__ ws) {
  int t = blockIdx.x * 256 + threadIdx.x; // 32768 threads
  int d = t & 15, m = (t >> 4) & 1023, b = t >> 14;
  float* hend = ws + OFF_HEND;
  const float* dtsum = ws + OFF_DTSUM;
  float A2 = ws[OFF_A2 + m * DD + d];
  const size_t hstride = (size_t)BB * MM * DD;
  const int sstride = BB * MM;
  size_t o = ((size_t)b * MM + m) * DD + d;
  int si = b * MM + m;
  float h = 0.f;
  float he = hend[o], S = dtsum[si];
  for (int c = 0; c < NCH; ++c) {
    float heN = 0.f, SN = 0.f;
    if (c + 1 < NCH) {
      heN = hend[o + hstride];
      SN = dtsum[si + sstride];
    }
    hend[o] = h;                  // h0 for chunk c
    h = vexp2(A2 * S) * h + he;
    he = heN; S = SN;
    o += hstride; si += sstride;
  }
}

// ---------------- scan phase 3: recompute with h0, emit y * silu(z). d-split x4 ----------------
__global__ __launch_bounds__(256) void k_scan3(const float* __restrict__ x,
                                               const float* __restrict__ z,
                                               const float* __restrict__ Dp,
                                               float* __restrict__ out,
                                               float* __restrict__ ws) {
  const float* xp = ws + OFF_XP;
  const float* A2t = ws + OFF_A2;
  const float* h0w = ws + OFF_HEND;      // phase 2 left h0 here
  __shared__ __align__(16) float ds_[CLEN * 64];
  __shared__ __align__(16) float xs_[CLEN * 64];
  __shared__ __align__(16) float zs_[CLEN * 64];
  __shared__ __align__(16) float bs[CLEN * 32];
  int wg = blockIdx.x;
  int mw = wg & 15, c = (wg >> 4) & (NCH - 1), b = wg >> 10;
  int t = threadIdx.x;
  int ml = t >> 2, dsub = t & 3;
  int m0 = mw * 64, m = m0 + ml;
  int l0 = c * CLEN;
  const unsigned short* dtg = (const unsigned short*)(ws + OFF_DT) + (size_t)(b * LL + l0) * MM + m0;
  const float* xg = x + (size_t)(b * LL + l0) * MM + m0;
  const float* zg = z + (size_t)(b * LL + l0) * MM + m0;
#pragma unroll
  for (int i = t; i < CLEN * 16; i += 256) {
    int lo = i >> 4, q = i & 15;
    u16x4 dv = *(const u16x4*)&dtg[(size_t)lo * MM + q * 4];
    *(float4*)&ds_[lo * 64 + q * 4] = make_float4(bf2f(dv[0]), bf2f(dv[1]), bf2f(dv[2]), bf2f(dv[3]));
    *(float4*)&xs_[lo * 64 + q * 4] = *(const float4*)&xg[(size_t)lo * MM + q * 4];
    *(float4*)&zs_[lo * 64 + q * 4] = *(const float4*)&zg[(size_t)lo * MM + q * 4];
  }
  for (int i = t; i < CLEN * 32; i += 256) {
    int r = i >> 5, cc = i & 31;
    bs[i] = xp[(size_t)(b * LL + l0 + r) * NN + RR + cc];
  }
  __syncthreads();
  float4 A2v = *(const float4*)&A2t[m * DD + dsub * 4];
  size_t o = ((size_t)((c * BB + b) * MM + m)) * DD + dsub * 4;
  float4 hv = *(const float4*)&h0w[o];
  float h0_ = hv.x, h1_ = hv.y, h2_ = hv.z, h3_ = hv.w;
  float Dpm = Dp[m];
  size_t idx = ((size_t)(b * LL + l0)) * MM + m;
#pragma unroll 4
  for (int lo = 0; lo < CLEN; ++lo) {
    float dtv = ds_[lo * 64 + ml];
    float xv = xs_[lo * 64 + ml];
    float zv = zs_[lo * 64 + ml];
    float4 Bv = *(const float4*)&bs[lo * 32 + dsub * 4];
    float4 Cv = *(const float4*)&bs[lo * 32 + DD + dsub * 4];
    float dtx = dtv * xv;
    h0_ = vexp2(dtv * A2v.x) * h0_ + dtx * Bv.x;
    h1_ = vexp2(dtv * A2v.y) * h1_ + dtx * Bv.y;
    h2_ = vexp2(dtv * A2v.z) * h2_ + dtx * Bv.z;
    h3_ = vexp2(dtv * A2v.w) * h3_ + dtx * Bv.w;
    float yp = h0_ * Cv.x + h1_ * Cv.y + h2_ * Cv.z + h3_ * Cv.w;
    yp += dpp_xor1(yp);
    yp += dpp_xor2(yp);
    float sig = __builtin_amdgcn_rcpf(1.f + vexp2(-LOG2E * zv));
    if (dsub == 0)
      out[idx + (size_t)lo * MM] = (yp + Dpm * xv) * zv * sig;
  }
}

extern "C" void kernel_launch(void* const* d_in, const int* in_sizes, int n_in,
                              void* d_out, int out_size, void* d_ws, size_t ws_size,
                              hipStream_t stream) {
  const float* x = (const float*)d_in[0];
  const float* z = (const float*)d_in[1];
  const float* W = (const float*)d_in[2];
  const float* dtW = (const float*)d_in[3];
  const float* dtb = (const float*)d_in[4];
  const float* A_log = (const float*)d_in[5];
  const float* Dp = (const float*)d_in[6];
  float* out = (float*)d_out;
  float* ws = (float*)d_ws;

  k_prep<<<224, 256, 0, stream>>>(W, dtW, A_log, ws);
  k_xp<<<(BLROWS / 16) * 3, 64, 0, stream>>>(x, ws);
  k_dt<<<(BLROWS / 16) * 8, 64, 0, stream>>>(dtb, ws);
  k_scan1<<<16 * NCH * BB, 256, 0, stream>>>(x, ws);
  k_scan2<<<128, 256, 0, stream>>>(ws);
  k_scan3<<<16 * NCH * BB, 256, 0, stream>>>(x, z, Dp, out, ws);
}